// Round 2
// baseline (16865.352 us; speedup 1.0000x reference)
//
#include <hip/hip_runtime.h>
#include <cstdint>

// Problem constants
#define Bsz 2048
#define Ssz 50
#define Esz 256
#define Hsz 512
#define Wsz 256
#define Lsz 50
#define Vsz 51

// ---------------- threefry2x32 (20 rounds), key words (k0,k1) ----------------
__host__ __device__ __forceinline__ void threefry2x32_hd(
    unsigned k0, unsigned k1, unsigned x0, unsigned x1,
    unsigned& o0, unsigned& o1) {
  unsigned ks2 = k0 ^ k1 ^ 0x1BD11BDAu;
  x0 += k0; x1 += k1;
#define TF_RND(r) { x0 += x1; x1 = (x1 << (r)) | (x1 >> (32 - (r))); x1 ^= x0; }
  TF_RND(13) TF_RND(15) TF_RND(26) TF_RND(6)
  x0 += k1; x1 += ks2 + 1u;
  TF_RND(17) TF_RND(29) TF_RND(16) TF_RND(24)
  x0 += ks2; x1 += k0 + 2u;
  TF_RND(13) TF_RND(15) TF_RND(26) TF_RND(6)
  x0 += k0; x1 += k1 + 3u;
  TF_RND(17) TF_RND(29) TF_RND(16) TF_RND(24)
  x0 += k1; x1 += ks2 + 4u;
  TF_RND(13) TF_RND(15) TF_RND(26) TF_RND(6)
  x0 += ks2; x1 += k0 + 5u;
#undef TF_RND
  o0 = x0; o1 = x1;
}

// ---------------- prep: Wpack[j][k][g] = Whh[g*512+j][k] ----------------
__global__ __launch_bounds__(256) void prep_pack(const float* __restrict__ src,
                                                 float* __restrict__ dst) {
  int idx = blockIdx.x * 256 + threadIdx.x;   // < 512*512
  int j = idx >> 9, k = idx & 511;
  float4 v;
  v.x = src[(size_t)(0 * 512 + j) * 512 + k];
  v.y = src[(size_t)(1 * 512 + j) * 512 + k];
  v.z = src[(size_t)(2 * 512 + j) * 512 + k];
  v.w = src[(size_t)(3 * 512 + j) * 512 + k];
  ((float4*)dst)[idx] = v;
}

// ---------------- prep: encInP[v][j][g] = emb[v].Wih[g*512+j] + bih + bhh ----
__global__ __launch_bounds__(256) void prep_encin(
    const float* __restrict__ emb, const float* __restrict__ Wih,
    const float* __restrict__ bih, const float* __restrict__ bhh,
    float* __restrict__ encInP) {
  int wid = blockIdx.x * 4 + (threadIdx.x >> 6);
  int lane = threadIdx.x & 63;
  if (wid >= Vsz * 2048) return;
  int v = wid >> 11, col = wid & 2047;
  float4 e = ((const float4*)emb)[v * 64 + lane];
  float4 w = ((const float4*)Wih)[col * 64 + lane];
  float d = e.x * w.x + e.y * w.y + e.z * w.z + e.w * w.w;
  for (int off = 32; off; off >>= 1) d += __shfl_xor(d, off);
  if (lane == 0) {
    int g = col >> 9, j = col & 511;
    encInP[(size_t)v * 2048 + j * 4 + g] = d + bih[col] + bhh[col];
  }
}

// ---------------- prep: dbiasP[j][g] = dec_bih + dec_bhh ----------------
__global__ __launch_bounds__(256) void prep_dbias(const float* __restrict__ a,
                                                  const float* __restrict__ b,
                                                  float* __restrict__ dst) {
  int col = blockIdx.x * 256 + threadIdx.x;  // < 2048
  int g = col >> 9, j = col & 511;
  dst[j * 4 + g] = a[col] + b[col];
}

// ---------------- prep: WtP[k4][w][i] = Wsrc[w][4*k4+i]  (for blend kernels) --
__global__ __launch_bounds__(256) void prep_wt(const float* __restrict__ src,
                                               float* __restrict__ dst) {
  int idx = blockIdx.x * 256 + threadIdx.x;  // < 128*256
  int k4 = idx >> 8, w = idx & 255;
  float4 v;
  v.x = src[(size_t)w * Hsz + k4 * 4 + 0];
  v.y = src[(size_t)w * Hsz + k4 * 4 + 1];
  v.z = src[(size_t)w * Hsz + k4 * 4 + 2];
  v.w = src[(size_t)w * Hsz + k4 * 4 + 3];
  ((float4*)dst)[idx] = v;
}

// ---------------- gates: LDS-free streaming GEMM + LSTM cell ----------------
// grid = 256 blocks: 128 b-groups (16 b) x 2 j-halves (256 j4 cols each).
// thread <-> j4 col c; W row (8KB) streams lane-local through L1;
// h[b][k] is wave-uniform (scalar path). Optional fused blend1 of hin.
__global__ __launch_bounds__(256) void gates_fused(
    const float* __restrict__ hin, const float* __restrict__ Wpack,
    const float* __restrict__ addtab, const int* __restrict__ input, int tstep,
    float* __restrict__ hout, float* __restrict__ cio,
    const float* __restrict__ W1P, float* __restrict__ b1row) {
  const int t = threadIdx.x;
  const int bgrp = blockIdx.x >> 1;
  const int jh = blockIdx.x & 1;
  const int bBase = bgrp * 16;

  // ---- phase A (encoder only): blend1 row for hin; 16b x 128w per block ----
  if (b1row) {
    const int w = (t & 127) + jh * 128;
    const int bh = t >> 7;  // 0..1, wave-uniform
    const float* __restrict__ hrows = hin + (size_t)(bBase + bh * 8) * Hsz;
    float acc2[8] = {0.f, 0.f, 0.f, 0.f, 0.f, 0.f, 0.f, 0.f};
#pragma unroll 4
    for (int k4 = 0; k4 < 128; ++k4) {
      float4 wv = ((const float4*)W1P)[k4 * 256 + w];
#pragma unroll
      for (int b = 0; b < 8; ++b) {
        float4 hv = ((const float4*)(hrows + (size_t)b * Hsz))[k4];
        acc2[b] = fmaf(hv.x, wv.x, acc2[b]);
        acc2[b] = fmaf(hv.y, wv.y, acc2[b]);
        acc2[b] = fmaf(hv.z, wv.z, acc2[b]);
        acc2[b] = fmaf(hv.w, wv.w, acc2[b]);
      }
    }
#pragma unroll
    for (int b = 0; b < 8; ++b)
      b1row[(size_t)(bBase + bh * 8 + b) * (Ssz * Wsz) + w] = acc2[b];
  }

  // ---- main GEMM: acc[b] (float4 = 4 gates) for column c, 16 b-rows ----
  const int c = jh * 256 + t;  // j4 col = j index, 0..511
  const float4* __restrict__ Wr = (const float4*)Wpack + (size_t)c * Hsz;
  const float* __restrict__ hb = hin + (size_t)bBase * Hsz;
  float4 acc[16];
#pragma unroll
  for (int b = 0; b < 16; ++b) acc[b] = make_float4(0.f, 0.f, 0.f, 0.f);

#pragma unroll 2
  for (int k4 = 0; k4 < 128; ++k4) {
    float4 w0 = Wr[k4 * 4 + 0];
    float4 w1 = Wr[k4 * 4 + 1];
    float4 w2 = Wr[k4 * 4 + 2];
    float4 w3 = Wr[k4 * 4 + 3];
#pragma unroll
    for (int b = 0; b < 16; ++b) {
      float4 hv = ((const float4*)(hb + (size_t)b * Hsz))[k4];  // wave-uniform
      float4 a = acc[b];
      a.x = fmaf(hv.x, w0.x, a.x); a.y = fmaf(hv.x, w0.y, a.y);
      a.z = fmaf(hv.x, w0.z, a.z); a.w = fmaf(hv.x, w0.w, a.w);
      a.x = fmaf(hv.y, w1.x, a.x); a.y = fmaf(hv.y, w1.y, a.y);
      a.z = fmaf(hv.y, w1.z, a.z); a.w = fmaf(hv.y, w1.w, a.w);
      a.x = fmaf(hv.z, w2.x, a.x); a.y = fmaf(hv.z, w2.y, a.y);
      a.z = fmaf(hv.z, w2.z, a.z); a.w = fmaf(hv.z, w2.w, a.w);
      a.x = fmaf(hv.w, w3.x, a.x); a.y = fmaf(hv.w, w3.y, a.y);
      a.z = fmaf(hv.w, w3.z, a.z); a.w = fmaf(hv.w, w3.w, a.w);
      acc[b] = a;
    }
  }

  // ---- epilogue: add input-proj/bias, LSTM nonlinearity, write c,h ----
#pragma unroll
  for (int b = 0; b < 16; ++b) {
    const int gb = bBase + b;
    const float4 av =
        ((const float4*)addtab)[(input ? (size_t)input[(size_t)gb * Ssz + tstep]
                                       : (size_t)0) * Hsz + c];
    float4 a = acc[b];
    float gi = a.x + av.x;
    float gf = a.y + av.y;
    float gg = a.z + av.z;
    float go = a.w + av.w;
    float si = 1.0f / (1.0f + expf(-gi));
    float sf = 1.0f / (1.0f + expf(-gf));
    float sg = tanhf(gg);
    float so = 1.0f / (1.0f + expf(-go));
    size_t oo = (size_t)gb * Hsz + c;
    float cn = sf * cio[oo] + si * sg;
    cio[oo] = cn;
    hout[oo] = so * tanhf(cn);
  }
}

// ---------------- standalone blend1 row (encoder tail, h_50 -> row 49) -------
__global__ __launch_bounds__(256) void blend1_row(
    const float* __restrict__ h, const float* __restrict__ W1P,
    float* __restrict__ b1, int srow) {
  const int t = threadIdx.x;
  const int bBase = blockIdx.x * 8;
  const float* __restrict__ hrows = h + (size_t)bBase * Hsz;
  float acc2[8] = {0.f, 0.f, 0.f, 0.f, 0.f, 0.f, 0.f, 0.f};
#pragma unroll 4
  for (int k4 = 0; k4 < 128; ++k4) {
    float4 wv = ((const float4*)W1P)[k4 * 256 + t];
#pragma unroll
    for (int b = 0; b < 8; ++b) {
      float4 hv = ((const float4*)(hrows + (size_t)b * Hsz))[k4];
      acc2[b] = fmaf(hv.x, wv.x, acc2[b]);
      acc2[b] = fmaf(hv.y, wv.y, acc2[b]);
      acc2[b] = fmaf(hv.z, wv.z, acc2[b]);
      acc2[b] = fmaf(hv.w, wv.w, acc2[b]);
    }
  }
#pragma unroll
  for (int b = 0; b < 8; ++b)
    b1[((size_t)(bBase + b) * Ssz + srow) * Wsz + t] = acc2[b];
}

// ---------------- decoder fused: blend2 + scores + log_softmax + sample ------
__global__ __launch_bounds__(256) void scores_fused(
    const float* __restrict__ hd, const float* __restrict__ W2P,
    const float* __restrict__ b1, const float* __restrict__ vt,
    unsigned long long* __restrict__ mask,
    float* __restrict__ probs, float* __restrict__ tour,
    int stepk, unsigned kA, unsigned kB) {
  __shared__ float b2s[8][256];
  __shared__ float vts[256];
  __shared__ float sc[8][64];
  const int t = threadIdx.x;
  const int bBase = blockIdx.x * 8;

  // ---- phase A: blend2[b][w] for 8 b, thread <-> w ----
  {
    const float* __restrict__ hrows = hd + (size_t)bBase * Hsz;
    float acc2[8] = {0.f, 0.f, 0.f, 0.f, 0.f, 0.f, 0.f, 0.f};
#pragma unroll 4
    for (int k4 = 0; k4 < 128; ++k4) {
      float4 wv = ((const float4*)W2P)[k4 * 256 + t];
#pragma unroll
      for (int b = 0; b < 8; ++b) {
        float4 hv = ((const float4*)(hrows + (size_t)b * Hsz))[k4];
        acc2[b] = fmaf(hv.x, wv.x, acc2[b]);
        acc2[b] = fmaf(hv.y, wv.y, acc2[b]);
        acc2[b] = fmaf(hv.z, wv.z, acc2[b]);
        acc2[b] = fmaf(hv.w, wv.w, acc2[b]);
      }
    }
#pragma unroll
    for (int b = 0; b < 8; ++b) b2s[b][t] = acc2[b];
    vts[t] = vt[t];
  }
  __syncthreads();

  // ---- phase B: scores rows (8 b x 50 s), one wave per row ----
  const int wave = t >> 6, lane = t & 63;
  for (int r = wave; r < 8 * Ssz; r += 4) {
    const int b = r / Ssz, s = r - b * Ssz;
    const float4* row = (const float4*)(b1 + ((size_t)(bBase + b) * Ssz + s) * Wsz);
    float4 rv = row[lane];
    float4 bv = *(const float4*)&b2s[b][lane * 4];
    float4 vv = *(const float4*)&vts[lane * 4];
    float v = vv.x * tanhf(rv.x + bv.x) + vv.y * tanhf(rv.y + bv.y) +
              vv.z * tanhf(rv.z + bv.z) + vv.w * tanhf(rv.w + bv.w);
    for (int off = 32; off; off >>= 1) v += __shfl_xor(v, off);
    if (lane == 0) sc[b][s] = v;
  }
  __syncthreads();

  // ---- phase C: mask, log_softmax, gumbel sample, mask update ----
  for (int bb = wave; bb < 8; bb += 4) {
    const int gb = bBase + bb;
    unsigned long long m = mask[gb];
    float x = (lane < Ssz) ? sc[bb][lane] : -INFINITY;
    if (lane < Ssz && ((m >> lane) & 1ull)) x = -100000.0f;
    float mv = x;
    for (int off = 32; off; off >>= 1) mv = fmaxf(mv, __shfl_xor(mv, off));
    float sh = x - mv;
    float e = (lane < Ssz) ? expf(sh) : 0.f;
    float ssum = e;
    for (int off = 32; off; off >>= 1) ssum += __shfl_xor(ssum, off);
    float lg = logf(ssum);
    float logp = sh - lg;
    if (lane < Ssz) probs[(size_t)gb * (Lsz * Ssz) + stepk * Ssz + lane] = logp;

    float val = -INFINITY;
    if (lane < Ssz) {
      unsigned j = (unsigned)(gb * Ssz + lane);
      unsigned o0, o1;
      threefry2x32_hd(kA, kB, 0u, j, o0, o1);
      unsigned bits = o0 ^ o1;
      float f = __uint_as_float((bits >> 9) | 0x3F800000u) - 1.0f;
      float u = fmaxf(1.17549435e-38f, f + 1.17549435e-38f);
      val = logp - logf(-logf(u));
    }
    int idx = lane;
    for (int off = 32; off; off >>= 1) {
      float ov = __shfl_xor(val, off);
      int oi = __shfl_xor(idx, off);
      if (ov > val || (ov == val && oi < idx)) { val = ov; idx = oi; }
    }
    if (lane == 0) {
      tour[(size_t)gb * Lsz + stepk] = (float)idx;
      mask[gb] = m | (1ull << idx);
    }
  }
}

extern "C" void kernel_launch(void* const* d_in, const int* in_sizes, int n_in,
                              void* d_out, int out_size, void* d_ws, size_t ws_size,
                              hipStream_t stream) {
  (void)in_sizes; (void)n_in; (void)out_size; (void)ws_size;
  const int*   input = (const int*)d_in[0];
  const float* emb   = (const float*)d_in[1];
  const float* eWih  = (const float*)d_in[2];
  const float* eWhh  = (const float*)d_in[3];
  const float* ebih  = (const float*)d_in[4];
  const float* ebhh  = (const float*)d_in[5];
  /* d_in[6] dec_Wih unused: decoder input is always zero */
  const float* dWhh  = (const float*)d_in[7];
  const float* dbih  = (const float*)d_in[8];
  const float* dbhh  = (const float*)d_in[9];
  const float* W1    = (const float*)d_in[10];
  const float* W2    = (const float*)d_in[11];
  const float* vt    = (const float*)d_in[12];
  float* outF = (float*)d_out;

  float* wsf = (float*)d_ws;
  size_t o = 0;
  float* WpackE = wsf + o; o += (size_t)512 * 512 * 4;
  float* WpackD = wsf + o; o += (size_t)512 * 512 * 4;
  float* encInP = wsf + o; o += (size_t)Vsz * 2048;
  float* dbiasP = wsf + o; o += 2048;
  float* W1P = wsf + o; o += (size_t)128 * 256 * 4;
  float* W2P = wsf + o; o += (size_t)128 * 256 * 4;
  float* hA  = wsf + o; o += (size_t)Bsz * Hsz;
  float* hB  = wsf + o; o += (size_t)Bsz * Hsz;
  float* cE  = wsf + o; o += (size_t)Bsz * Hsz;
  float* hdA = wsf + o; o += (size_t)Bsz * Hsz;
  float* hdB = wsf + o; o += (size_t)Bsz * Hsz;
  float* cD  = wsf + o; o += (size_t)Bsz * Hsz;
  float* b1  = wsf + o; o += (size_t)Bsz * Ssz * Wsz;
  unsigned long long* maskp = (unsigned long long*)(wsf + o); o += Bsz * 2;

  hipMemsetAsync(hA, 0, (size_t)Bsz * Hsz * 4, stream);
  hipMemsetAsync(cE, 0, (size_t)Bsz * Hsz * 4, stream);
  hipMemsetAsync(hdA, 0, (size_t)Bsz * Hsz * 4, stream);
  hipMemsetAsync(maskp, 0, (size_t)Bsz * 8, stream);

  prep_pack<<<1024, 256, 0, stream>>>(eWhh, WpackE);
  prep_pack<<<1024, 256, 0, stream>>>(dWhh, WpackD);
  prep_encin<<<(Vsz * 2048) / 4, 256, 0, stream>>>(emb, eWih, ebih, ebhh, encInP);
  prep_dbias<<<8, 256, 0, stream>>>(dbih, dbhh, dbiasP);
  prep_wt<<<128, 256, 0, stream>>>(W1, W1P);
  prep_wt<<<128, 256, 0, stream>>>(W2, W2P);

  // host-side: step keys = jax.random.split(jax.random.key(42), 50)
  unsigned kAh[Lsz], kBh[Lsz];
  for (int k = 0; k < Lsz; ++k)
    threefry2x32_hd(0u, 42u, 0u, (unsigned)k, kAh[k], kBh[k]);

  // encoder: step t computes h_{t+1}; fused blend1 handles hin = h_t (row t-1)
  float* hr = hA; float* hw = hB;
  for (int t = 0; t < Ssz; ++t) {
    float* b1row = (t >= 1) ? (b1 + (size_t)(t - 1) * Wsz) : nullptr;
    gates_fused<<<256, 256, 0, stream>>>(hr, WpackE, encInP, input, t, hw, cE,
                                         W1P, b1row);
    float* tp = hr; hr = hw; hw = tp;
  }
  blend1_row<<<256, 256, 0, stream>>>(hr, W1P, b1, Ssz - 1);  // h_50 -> row 49

  // decoder init: c0 = last encoder h, h0 = 0 (hdA), mask = 0
  hipMemcpyAsync(cD, hr, (size_t)Bsz * Hsz * 4, hipMemcpyDeviceToDevice, stream);

  float* dr = hdA; float* dw = hdB;
  for (int k = 0; k < Lsz; ++k) {
    gates_fused<<<256, 256, 0, stream>>>(dr, WpackD, dbiasP, nullptr, 0, dw, cD,
                                         nullptr, nullptr);
    scores_fused<<<256, 256, 0, stream>>>(dw, W2P, b1, vt, maskp, outF,
                                          outF + (size_t)Bsz * Lsz * Ssz,
                                          k, kAh[k], kBh[k]);
    float* tp = dr; dr = dw; dw = tp;
  }
}